// Round 1
// baseline (39.050 us; speedup 1.0000x reference)
//
#include <hip/hip_runtime.h>

// EigVals: per-voxel symmetric 3x3 eigenvalues (ascending), closed-form.
// Input  x: (B=2, 9, D*H*W=2359296) float32, channel c = row-major 3x3 entry.
// Output  : (B*D*H*W, 3) float32 ascending eigenvalues of 0.5*(M + M^T).

__global__ __launch_bounds__(256) void eig3_kernel(const float* __restrict__ x,
                                                   float* __restrict__ out,
                                                   int nper,     // voxels per batch (D*H*W)
                                                   int total4)   // total voxels / 4
{
    int t = blockIdx.x * 256 + threadIdx.x;
    if (t >= total4) return;

    long long v = (long long)t * 4;           // first voxel handled by this thread
    int       b = (int)(v / nper);            // batch index (group of 4 never crosses: nper%4==0)
    long long n = v - (long long)b * nper;
    const float* base = x + (long long)b * 9ll * nper + n;

    // 9 coalesced float4 streams, one per matrix entry channel
    float mv[9][4];
#pragma unroll
    for (int c = 0; c < 9; ++c) {
        float4 f = *reinterpret_cast<const float4*>(base + (long long)c * nper);
        mv[c][0] = f.x; mv[c][1] = f.y; mv[c][2] = f.z; mv[c][3] = f.w;
    }

    float r[12];
#pragma unroll
    for (int k = 0; k < 4; ++k) {
        // symmetrize: A = 0.5*(M + M^T)
        float a00 = mv[0][k], a11 = mv[4][k], a22 = mv[8][k];
        float a01 = 0.5f * (mv[1][k] + mv[3][k]);
        float a02 = 0.5f * (mv[2][k] + mv[6][k]);
        float a12 = 0.5f * (mv[5][k] + mv[7][k]);

        // Smith's trigonometric method
        float q   = (a00 + a11 + a22) * (1.0f / 3.0f);
        float b00 = a00 - q, b11 = a11 - q, b22 = a22 - q;
        float p1  = a01 * a01 + a02 * a02 + a12 * a12;
        float p2  = b00 * b00 + b11 * b11 + b22 * b22 + 2.0f * p1;
        float p   = sqrtf(p2 * (1.0f / 6.0f));
        float ip  = (p2 > 1e-30f) ? (1.0f / p) : 0.0f;  // p->0: all eigs = q (branchless fallout)

        float c00 = b00 * ip, c11 = b11 * ip, c22 = b22 * ip;
        float c01 = a01 * ip, c02 = a02 * ip, c12 = a12 * ip;

        float det = c00 * (c11 * c22 - c12 * c12)
                  - c01 * (c01 * c22 - c12 * c02)
                  + c02 * (c01 * c12 - c11 * c02);
        float rr  = fminf(fmaxf(0.5f * det, -1.0f), 1.0f);
        float phi = acosf(rr) * (1.0f / 3.0f);

        const float TWO_PI_3 = 2.0943951023931953f;
        float c_hi  = cosf(phi);                   // largest
        float c_lo  = cosf(phi + TWO_PI_3);        // smallest
        float c_mid = cosf(phi + 2.0f * TWO_PI_3); // middle

        float two_p = 2.0f * p;
        r[3 * k + 0] = q + two_p * c_lo;
        r[3 * k + 1] = q + two_p * c_mid;
        r[3 * k + 2] = q + two_p * c_hi;
    }

    // 12 consecutive output floats (voxel-major, 3 per voxel) -> 3x float4
    float4* o = reinterpret_cast<float4*>(out + v * 3);
    o[0] = make_float4(r[0], r[1],  r[2],  r[3]);
    o[1] = make_float4(r[4], r[5],  r[6],  r[7]);
    o[2] = make_float4(r[8], r[9],  r[10], r[11]);
}

extern "C" void kernel_launch(void* const* d_in, const int* in_sizes, int n_in,
                              void* d_out, int out_size, void* d_ws, size_t ws_size,
                              hipStream_t stream) {
    const float* x  = (const float*)d_in[0];
    float*       out = (float*)d_out;

    // x: (B=2, 9, nper). in_sizes[0] = 2*9*nper.
    const int nper   = in_sizes[0] / 18;       // 2359296
    const int totalv = in_sizes[0] / 9;        // 4718592 voxels
    const int total4 = totalv / 4;             // 1179648 threads
    const int blocks = (total4 + 255) / 256;   // 4608

    eig3_kernel<<<blocks, 256, 0, stream>>>(x, out, nper, total4);
}